// Round 22
// baseline (90.639 us; speedup 1.0000x reference)
//
#include <hip/hip_runtime.h>
#include <hip/hip_bf16.h>
#include <hip/hip_fp8.h>

// B=16,S=4096,H=512 ; G=2,V=320,D=256 (Dg=128)
constexpr int BT = 65536;
constexpr int K  = 512;
constexpr int V  = 320;
constexpr int G  = 2;
constexpr int Dg = 128;
constexpr int MT = 64;           // rows per block; 8 waves = 2 row-halves x 4 col-quarters
constexpr int NSTEP = 8;         // K/64
constexpr size_t WS_IMG = 4096;  // frag-ordered e4m3 B img (320 KB), kk-paired 16B chunks

using f32x4 = __attribute__((ext_vector_type(4))) float;

static __device__ __forceinline__ unsigned cvt4(float a, float b, float c, float d) {
#if __has_builtin(__builtin_amdgcn_cvt_pk_fp8_f32)
    int r = 0;
    r = __builtin_amdgcn_cvt_pk_fp8_f32(a, b, r, false);   // bytes 0-1
    r = __builtin_amdgcn_cvt_pk_fp8_f32(c, d, r, true);    // bytes 2-3
    return (unsigned)r;
#else
    __hip_fp8_e4m3 ha(a), hb(b), hc(c), hd(d);
    return (unsigned)ha.__x | ((unsigned)hb.__x << 8) |
           ((unsigned)hc.__x << 16) | ((unsigned)hd.__x << 24);
#endif
}
static __device__ __forceinline__ long long mk64(unsigned lo, unsigned hi) {
    return (long long)(((unsigned long long)hi << 32) | lo);
}
static __device__ __forceinline__ f32x4 mfma_fp8(long long a, long long b, f32x4 c) {
    return __builtin_amdgcn_mfma_f32_16x16x32_fp8_fp8(a, b, c, 0, 0, 0);
}

// ---- prep: e4m3 image of W' = 16*W, kk-PAIRED 16B chunks (R18 layout, unchanged) ----
// chunk id = (((g*8+s)*4+wc)*5+nt)*64+lane, 16 B = [kk0: k=s*64+(lane>>4)*8+j | kk1: k=+32],
// col = g*320+wc*80+nt*16+(lane&15)
__global__ __launch_bounds__(256) void vq_prep(const float* __restrict__ Wm,
                                               unsigned char* __restrict__ img)
{
    int id   = blockIdx.x * 256 + threadIdx.x;   // 0..20479 (grid 80)
    int lane = id & 63;
    int r    = id >> 6;
    int nt   = r % 5;  r /= 5;
    int wc   = r & 3;  r >>= 2;
    int s    = r & 7;
    int g    = r >> 3;
    int col  = g * V + wc * 80 + nt * 16 + (lane & 15);
    int kb   = s * 64 + (lane >> 4) * 8;
    float v0[8], v1[8];
#pragma unroll
    for (int j = 0; j < 8; ++j) {
        v0[j] = 16.0f * Wm[(size_t)(kb + j) * 640 + col];
        v1[j] = 16.0f * Wm[(size_t)(kb + 32 + j) * 640 + col];
    }
    *reinterpret_cast<uint4*>(img + (size_t)id * 16) =
        make_uint4(cvt4(v0[0], v0[1], v0[2], v0[3]), cvt4(v0[4], v0[5], v0[6], v0[7]),
                   cvt4(v1[0], v1[1], v1[2], v1[3]), cvt4(v1[4], v1[5], v1[6], v1[7]));
}

// ---- main: fp8 MFMA GEMM (64x320x512), BK=64, DOUBLE-BUFFERED single-barrier step ----
// Per step: issue B(s+1) DMA -> Bbuf^1 + A(s+2) globals (pinned first), pack A(s+1)
// -> Abuf^1, compute step s from cur buffers, ONE __syncthreads (its drain retires
// the DMA issued at step top -> 20KB B transfer overlaps the MFMA cluster).
// LDS 48KB: A dbuf 2x4KB @0 ; B dbuf 2x20KB @8192. grid 2048.
__global__ __launch_bounds__(512) void vq_main(
    const float* __restrict__ hs, const unsigned char* __restrict__ img,
    const float* __restrict__ bv, const float* __restrict__ cbv,
    float* __restrict__ out, unsigned int* __restrict__ hist)
{
    __shared__ __align__(16) unsigned char smem[49152];

    const int tid  = threadIdx.x;
    const int bid  = blockIdx.x;
    const int g    = (bid >> 3) & 1;
    const int rblk = (bid & 7) | ((bid >> 4) << 3);
    const int r0   = rblk * MT;
    const int w    = tid >> 6;
    const int lane = tid & 63;
    const int l4   = lane & 15;
    const int wc   = w & 3;        // col quarter (80 cols)
    const int h    = w >> 2;       // row half (32 rows)

    f32x4 acc[2][5] = {};

    // A staging: thread -> row tid>>3 (0..63), akq = tid&7 -> 8 floats (k = akq*8..+7)
    const int arow = tid >> 3, akq = tid & 7;
    const float* aptr = hs + (size_t)(r0 + arow) * K + akq * 8;
    const int awoff = (arow >> 4) * 1024 + ((arow & 15) + 16 * (akq & 3)) * 16 + (akq >> 2) * 8;
    // A frag read bases (b128, contiguous 1024B/wave = conflict-free); + cur*4096
    const int a_rd0 = (h * 2 + 0) * 1024 + lane * 16;
    const int a_rd1 = (h * 2 + 1) * 1024 + lane * 16;
    // B: DMA linear; read per (wc,nt) contiguous; + cur*20480
    const unsigned char* bsrc = img + (size_t)g * 163840 + (size_t)tid * 16;
    const int b_rd = 8192 + wc * 5 * 1024 + lane * 16;   // + cur*20480 + nt*1024

    auto issueB = [&](int s, int buf) {
        const unsigned char* bs = bsrc + (size_t)s * 20480;
        const int dst = 8192 + buf * 20480;
#pragma unroll
        for (int i = 0; i < 2; ++i)
            __builtin_amdgcn_global_load_lds(
                (const __attribute__((address_space(1))) void*)(bs + i * 8192),
                (__attribute__((address_space(3))) void*)(&smem[dst + i * 8192 + tid * 16]),
                16, 0, 0);
        if (tid < 256)
            __builtin_amdgcn_global_load_lds(
                (const __attribute__((address_space(1))) void*)(bs + 16384),
                (__attribute__((address_space(3))) void*)(&smem[dst + 16384 + tid * 16]),
                16, 0, 0);
    };
    auto packA = [&](float4 x, float4 y, int buf) {
        *reinterpret_cast<uint2*>(&smem[buf * 4096 + awoff]) =
            make_uint2(cvt4(x.x, x.y, x.z, x.w), cvt4(y.x, y.y, y.z, y.w));
    };

    // ---- prologue: B(0) DMA + A(0) packed into buf0; A(1) in regs; one barrier ----
    float4 aX[2], aY[2];
    aX[0] = *reinterpret_cast<const float4*>(aptr);          // A(0)
    aY[0] = *reinterpret_cast<const float4*>(aptr + 4);
    issueB(0, 0);
    aX[1] = *reinterpret_cast<const float4*>(aptr + 64);     // A(1)
    aY[1] = *reinterpret_cast<const float4*>(aptr + 64 + 4);
    packA(aX[0], aY[0], 0);          // auto-waits A(0) only (oldest in queue)
    __syncthreads();                 // drains B(0) DMA + A(1) + packA write

#pragma unroll
    for (int s = 0; s < NSTEP; ++s) {
        const int cur = s & 1, nxt = cur ^ 1;
        // issue next-step transfers FIRST (they drain at this step's barrier,
        // flowing under the MFMA cluster)
        if (s + 1 < NSTEP) issueB(s + 1, nxt);
        if (s + 2 < NSTEP) {
            aX[cur] = *reinterpret_cast<const float4*>(aptr + (s + 2) * 64);
            aY[cur] = *reinterpret_cast<const float4*>(aptr + (s + 2) * 64 + 4);
        }
        __builtin_amdgcn_sched_barrier(0);       // pin issue cluster above compute
        if (s + 1 < NSTEP) packA(aX[nxt], aY[nxt], nxt);   // A(s+1), loaded last step
        // ---- compute step s from cur buffers ----
        __builtin_amdgcn_s_setprio(1);           // T5
        {
            uint4 a0 = *reinterpret_cast<const uint4*>(&smem[cur * 4096 + a_rd0]);
            uint4 a1 = *reinterpret_cast<const uint4*>(&smem[cur * 4096 + a_rd1]);
            long long a0k0 = mk64(a0.x, a0.y), a0k1 = mk64(a0.z, a0.w);
            long long a1k0 = mk64(a1.x, a1.y), a1k1 = mk64(a1.z, a1.w);
#pragma unroll
            for (int nt = 0; nt < 5; ++nt) {
                uint4 bb = *reinterpret_cast<const uint4*>(
                    &smem[b_rd + cur * 20480 + nt * 1024]);
                long long bk0 = mk64(bb.x, bb.y), bk1 = mk64(bb.z, bb.w);
                acc[0][nt] = mfma_fp8(a0k0, bk0, acc[0][nt]);   // kk=0 first,
                acc[0][nt] = mfma_fp8(a0k1, bk1, acc[0][nt]);   // kk=1 second (R18 order)
                acc[1][nt] = mfma_fp8(a1k0, bk0, acc[1][nt]);
                acc[1][nt] = mfma_fp8(a1k1, bk1, acc[1][nt]);
            }
        }
        __builtin_amdgcn_s_setprio(0);
        __syncthreads();   // single barrier: drains B(s+1) DMA + packA; flips buffers
    }

    // ---- epilogue: bias (x16 to match scaled logits) + argmax ----
    float biasv[5];
#pragma unroll
    for (int nt = 0; nt < 5; ++nt) biasv[nt] = 16.0f * bv[g * V + wc * 80 + nt * 16 + l4];

    float* red_v = reinterpret_cast<float*>(smem);          // [64][4]
    int*   red_i = reinterpret_cast<int*>(smem + 1024);     // [64][4]
    int*   idx_s = reinterpret_cast<int*>(smem + 2048);     // [64]

#pragma unroll
    for (int mt = 0; mt < 2; ++mt) {
#pragma unroll
        for (int reg = 0; reg < 4; ++reg) {
            float bestv = acc[mt][0][reg] + biasv[0];
            int   besti = wc * 80 + l4;
#pragma unroll
            for (int nt = 1; nt < 5; ++nt) {
                float v = acc[mt][nt][reg] + biasv[nt];
                int   ci = wc * 80 + nt * 16 + l4;
                if (v > bestv) { bestv = v; besti = ci; }
            }
#pragma unroll
            for (int m = 1; m < 16; m <<= 1) {
                float ov = __shfl_xor(bestv, m);
                int   oi = __shfl_xor(besti, m);
                if (ov > bestv || (ov == bestv && oi < besti)) { bestv = ov; besti = oi; }
            }
            if (l4 == 0) {
                int row = h * 32 + mt * 16 + (lane >> 4) * 4 + reg;
                red_v[row * 4 + wc] = bestv;
                red_i[row * 4 + wc] = besti;
            }
        }
    }
    __syncthreads();

    int my_bi = -1;
    if (tid < MT) {
        float bb = red_v[tid * 4]; int bi = red_i[tid * 4];
#pragma unroll
        for (int c = 1; c < 4; ++c) {
            float v = red_v[tid * 4 + c]; int ii = red_i[tid * 4 + c];
            if (v > bb || (v == bb && ii < bi)) { bb = v; bi = ii; }
        }
        idx_s[tid] = bi;
        my_bi = bi;
    }
    __syncthreads();

    // ---- gather: 64 rows x 32 float4 = 2048 chunks, 4 per thread ----
#pragma unroll
    for (int i = 0; i < 4; ++i) {
        int idx = i * 512 + tid;
        int row = idx >> 5;
        int d4  = idx & 31;
        int vi  = idx_s[row];
        float4 val = *reinterpret_cast<const float4*>(&cbv[((size_t)(g * V + vi)) * Dg + d4 * 4]);
        *reinterpret_cast<float4*>(&out[((size_t)(r0 + row)) * (G * Dg) + g * Dg + d4 * 4]) = val;
    }
    if (my_bi >= 0) atomicAdd(&hist[g * V + my_bi], 1u);   // last: no post-atomic drain
}

// Perplexity from histogram: one wave.
__global__ void vq_ppl(const unsigned int* __restrict__ hist, float* __restrict__ outp)
{
    int lane = threadIdx.x;  // 64
    float ppl = 0.0f;
    for (int g = 0; g < G; ++g) {
        float local = 0.0f;
        for (int v = lane; v < V; v += 64) {
            float m = (float)hist[g * V + v] * (1.0f / (float)BT);
            local += m * logf(m + 1e-7f);
        }
#pragma unroll
        for (int off = 32; off; off >>= 1) local += __shfl_down(local, off);
        if (lane == 0) ppl += expf(-local);
    }
    if (lane == 0) outp[0] = ppl;
}

extern "C" void kernel_launch(void* const* d_in, const int* in_sizes, int n_in,
                              void* d_out, int out_size, void* d_ws, size_t ws_size,
                              hipStream_t stream)
{
    const float* hs  = (const float*)d_in[0];   // (65536, 512)
    const float* Wm  = (const float*)d_in[1];   // (512, 640)
    const float* bv  = (const float*)d_in[2];   // (640,)
    const float* cbv = (const float*)d_in[3];   // (640, 128)
    float* out = (float*)d_out;                 // 65536*256 floats + 1 float perplexity

    unsigned int*  hist = (unsigned int*)d_ws;
    unsigned char* img  = (unsigned char*)d_ws + WS_IMG;

    hipMemsetAsync(d_ws, 0, G * V * sizeof(unsigned int), stream);
    vq_prep<<<80, 256, 0, stream>>>(Wm, img);
    vq_main<<<2048, 512, 0, stream>>>(hs, img, bv, cbv, out, hist);
    vq_ppl<<<1, 64, 0, stream>>>(hist, out + (size_t)BT * G * Dg);
}

// Round 23
// 84.744 us; speedup vs baseline: 1.0696x; 1.0696x over previous
//
#include <hip/hip_runtime.h>
#include <hip/hip_bf16.h>
#include <hip/hip_fp8.h>

// B=16,S=4096,H=512 ; G=2,V=320,D=256 (Dg=128)
constexpr int BT = 65536;
constexpr int K  = 512;
constexpr int V  = 320;
constexpr int G  = 2;
constexpr int Dg = 128;
constexpr int MT = 64;           // rows per block; 8 waves = 2 row-halves x 4 col-quarters
constexpr int NSTEP = 8;         // K/64
constexpr size_t WS_IMG = 4096;  // frag-ordered e4m3 B img (320 KB), kk-paired 16B chunks

using f32x4 = __attribute__((ext_vector_type(4))) float;

static __device__ __forceinline__ unsigned cvt4(float a, float b, float c, float d) {
#if __has_builtin(__builtin_amdgcn_cvt_pk_fp8_f32)
    int r = 0;
    r = __builtin_amdgcn_cvt_pk_fp8_f32(a, b, r, false);   // bytes 0-1
    r = __builtin_amdgcn_cvt_pk_fp8_f32(c, d, r, true);    // bytes 2-3
    return (unsigned)r;
#else
    __hip_fp8_e4m3 ha(a), hb(b), hc(c), hd(d);
    return (unsigned)ha.__x | ((unsigned)hb.__x << 8) |
           ((unsigned)hc.__x << 16) | ((unsigned)hd.__x << 24);
#endif
}
static __device__ __forceinline__ long long mk64(unsigned lo, unsigned hi) {
    return (long long)(((unsigned long long)hi << 32) | lo);
}
static __device__ __forceinline__ f32x4 mfma_fp8(long long a, long long b, f32x4 c) {
    return __builtin_amdgcn_mfma_f32_16x16x32_fp8_fp8(a, b, c, 0, 0, 0);
}

// ---- prep: e4m3 image of W' = 16*W, kk-PAIRED 16B chunks ----
// chunk id = (((g*8+s)*4+wc)*5+nt)*64+lane, 16 B = [kk0: k=s*64+(lane>>4)*8+j]
// [kk1: k=+32], col = g*320+wc*80+nt*16+(lane&15)
__global__ __launch_bounds__(256) void vq_prep(const float* __restrict__ Wm,
                                               unsigned char* __restrict__ img)
{
    int id   = blockIdx.x * 256 + threadIdx.x;   // 0..20479 (grid 80)
    int lane = id & 63;
    int r    = id >> 6;
    int nt   = r % 5;  r /= 5;
    int wc   = r & 3;  r >>= 2;
    int s    = r & 7;
    int g    = r >> 3;
    int col  = g * V + wc * 80 + nt * 16 + (lane & 15);
    int kb   = s * 64 + (lane >> 4) * 8;
    float v0[8], v1[8];
#pragma unroll
    for (int j = 0; j < 8; ++j) {
        v0[j] = 16.0f * Wm[(size_t)(kb + j) * 640 + col];
        v1[j] = 16.0f * Wm[(size_t)(kb + 32 + j) * 640 + col];
    }
    *reinterpret_cast<uint4*>(img + (size_t)id * 16) =
        make_uint4(cvt4(v0[0], v0[1], v0[2], v0[3]), cvt4(v0[4], v0[5], v0[6], v0[7]),
                   cvt4(v1[0], v1[1], v1[2], v1[3]), cvt4(v1[4], v1[5], v1[6], v1[7]));
}

// ---- main: fp8 MFMA GEMM (64x320x512), BK=64, b128 LDS accesses (R18 = session best) ----
// LDS 24KB: A [0,4K): region (row>>4)*1024 + lane*16 (16B = kk0|kk1 frag pair);
//           B [4K,24K): (wc*5+nt)*1024 + lane*16 (kk-paired chunks, linear DMA).
// grid 2048: g=(bid>>3)&1, rblk=(bid&7)|((bid>>4)<<3).
__global__ __launch_bounds__(512) void vq_main(
    const float* __restrict__ hs, const unsigned char* __restrict__ img,
    const float* __restrict__ bv, const float* __restrict__ cbv,
    float* __restrict__ out, unsigned int* __restrict__ hist)
{
    __shared__ __align__(16) unsigned char smem[24576];

    const int tid  = threadIdx.x;
    const int bid  = blockIdx.x;
    const int g    = (bid >> 3) & 1;
    const int rblk = (bid & 7) | ((bid >> 4) << 3);
    const int r0   = rblk * MT;
    const int w    = tid >> 6;
    const int lane = tid & 63;
    const int l4   = lane & 15;
    const int wc   = w & 3;        // col quarter (80 cols)
    const int h    = w >> 2;       // row half (32 rows)

    f32x4 acc[2][5] = {};

    // A staging: thread -> row tid>>3 (0..63), akq = tid&7 -> 8 floats (k = akq*8..+7)
    const int arow = tid >> 3, akq = tid & 7;
    const float* aptr = hs + (size_t)(r0 + arow) * K + akq * 8;
    const int awoff = (arow >> 4) * 1024 + ((arow & 15) + 16 * (akq & 3)) * 16 + (akq >> 2) * 8;
    // A frag read bases (b128, contiguous 1024B/wave = conflict-free)
    const int a_rd0 = (h * 2 + 0) * 1024 + lane * 16;
    const int a_rd1 = (h * 2 + 1) * 1024 + lane * 16;
    // B: DMA linear; read per (wc,nt) contiguous
    const unsigned char* bsrc = img + (size_t)g * 163840 + (size_t)tid * 16;
    const int b_rd = 4096 + wc * 5 * 1024 + lane * 16;   // + nt*1024

    auto packA = [&](float4 x, float4 y) {
        *reinterpret_cast<uint2*>(&smem[awoff]) =
            make_uint2(cvt4(x.x, x.y, x.z, x.w), cvt4(y.x, y.y, y.z, y.w));
    };

    // prologue: A(0) in flight
    float4 ax = *reinterpret_cast<const float4*>(aptr);
    float4 ay = *reinterpret_cast<const float4*>(aptr + 4);

    for (int s = 0; s < NSTEP; ++s) {
        // ---- stage: B step-region (20KB) via LDS-DMA, A (4KB) convert+write ----
        const unsigned char* bs = bsrc + (size_t)s * 20480;
#pragma unroll
        for (int i = 0; i < 2; ++i)
            __builtin_amdgcn_global_load_lds(
                (const __attribute__((address_space(1))) void*)(bs + i * 8192),
                (__attribute__((address_space(3))) void*)(&smem[4096 + i * 8192 + tid * 16]),
                16, 0, 0);
        if (tid < 256)
            __builtin_amdgcn_global_load_lds(
                (const __attribute__((address_space(1))) void*)(bs + 16384),
                (__attribute__((address_space(3))) void*)(&smem[4096 + 16384 + tid * 16]),
                16, 0, 0);
        packA(ax, ay);                    // auto-waits A(s) only
        __syncthreads();                  // drains B DMA + LDS writes
        // ---- compute; A(s+1) issued first so HBM latency hides under MFMA ----
        if (s + 1 < NSTEP) {
            ax = *reinterpret_cast<const float4*>(aptr + (s + 1) * 64);
            ay = *reinterpret_cast<const float4*>(aptr + (s + 1) * 64 + 4);
        }
        __builtin_amdgcn_s_setprio(1);            // T5
        {
            uint4 a0 = *reinterpret_cast<const uint4*>(&smem[a_rd0]);
            uint4 a1 = *reinterpret_cast<const uint4*>(&smem[a_rd1]);
            long long a0k0 = mk64(a0.x, a0.y), a0k1 = mk64(a0.z, a0.w);
            long long a1k0 = mk64(a1.x, a1.y), a1k1 = mk64(a1.z, a1.w);
#pragma unroll
            for (int nt = 0; nt < 5; ++nt) {
                uint4 bb = *reinterpret_cast<const uint4*>(&smem[b_rd + nt * 1024]);
                long long bk0 = mk64(bb.x, bb.y), bk1 = mk64(bb.z, bb.w);
                acc[0][nt] = mfma_fp8(a0k0, bk0, acc[0][nt]);   // kk=0 first,
                acc[0][nt] = mfma_fp8(a0k1, bk1, acc[0][nt]);   // kk=1 second
                acc[1][nt] = mfma_fp8(a1k0, bk0, acc[1][nt]);
                acc[1][nt] = mfma_fp8(a1k1, bk1, acc[1][nt]);
            }
        }
        __builtin_amdgcn_s_setprio(0);
        __syncthreads();                  // buffer reuse guard
    }

    // ---- epilogue: bias (x16 to match scaled logits) + argmax ----
    float biasv[5];
#pragma unroll
    for (int nt = 0; nt < 5; ++nt) biasv[nt] = 16.0f * bv[g * V + wc * 80 + nt * 16 + l4];

    float* red_v = reinterpret_cast<float*>(smem);          // [64][4]
    int*   red_i = reinterpret_cast<int*>(smem + 1024);     // [64][4]
    int*   idx_s = reinterpret_cast<int*>(smem + 2048);     // [64]

#pragma unroll
    for (int mt = 0; mt < 2; ++mt) {
#pragma unroll
        for (int reg = 0; reg < 4; ++reg) {
            float bestv = acc[mt][0][reg] + biasv[0];
            int   besti = wc * 80 + l4;
#pragma unroll
            for (int nt = 1; nt < 5; ++nt) {
                float v = acc[mt][nt][reg] + biasv[nt];
                int   ci = wc * 80 + nt * 16 + l4;
                if (v > bestv) { bestv = v; besti = ci; }
            }
#pragma unroll
            for (int m = 1; m < 16; m <<= 1) {
                float ov = __shfl_xor(bestv, m);
                int   oi = __shfl_xor(besti, m);
                if (ov > bestv || (ov == bestv && oi < besti)) { bestv = ov; besti = oi; }
            }
            if (l4 == 0) {
                int row = h * 32 + mt * 16 + (lane >> 4) * 4 + reg;
                red_v[row * 4 + wc] = bestv;
                red_i[row * 4 + wc] = besti;
            }
        }
    }
    __syncthreads();

    int my_bi = -1;
    if (tid < MT) {
        float bb = red_v[tid * 4]; int bi = red_i[tid * 4];
#pragma unroll
        for (int c = 1; c < 4; ++c) {
            float v = red_v[tid * 4 + c]; int ii = red_i[tid * 4 + c];
            if (v > bb || (v == bb && ii < bi)) { bb = v; bi = ii; }
        }
        idx_s[tid] = bi;
        my_bi = bi;
    }
    __syncthreads();

    // ---- gather: 64 rows x 32 float4 = 2048 chunks, 4 per thread ----
#pragma unroll
    for (int i = 0; i < 4; ++i) {
        int idx = i * 512 + tid;
        int row = idx >> 5;
        int d4  = idx & 31;
        int vi  = idx_s[row];
        float4 val = *reinterpret_cast<const float4*>(&cbv[((size_t)(g * V + vi)) * Dg + d4 * 4]);
        *reinterpret_cast<float4*>(&out[((size_t)(r0 + row)) * (G * Dg) + g * Dg + d4 * 4]) = val;
    }
    if (my_bi >= 0) atomicAdd(&hist[g * V + my_bi], 1u);   // last: no post-atomic drain
}

// Perplexity from histogram: one wave.
__global__ void vq_ppl(const unsigned int* __restrict__ hist, float* __restrict__ outp)
{
    int lane = threadIdx.x;  // 64
    float ppl = 0.0f;
    for (int g = 0; g < G; ++g) {
        float local = 0.0f;
        for (int v = lane; v < V; v += 64) {
            float m = (float)hist[g * V + v] * (1.0f / (float)BT);
            local += m * logf(m + 1e-7f);
        }
#pragma unroll
        for (int off = 32; off; off >>= 1) local += __shfl_down(local, off);
        if (lane == 0) ppl += expf(-local);
    }
    if (lane == 0) outp[0] = ppl;
}

extern "C" void kernel_launch(void* const* d_in, const int* in_sizes, int n_in,
                              void* d_out, int out_size, void* d_ws, size_t ws_size,
                              hipStream_t stream)
{
    const float* hs  = (const float*)d_in[0];   // (65536, 512)
    const float* Wm  = (const float*)d_in[1];   // (512, 640)
    const float* bv  = (const float*)d_in[2];   // (640,)
    const float* cbv = (const float*)d_in[3];   // (640, 128)
    float* out = (float*)d_out;                 // 65536*256 floats + 1 float perplexity

    unsigned int*  hist = (unsigned int*)d_ws;
    unsigned char* img  = (unsigned char*)d_ws + WS_IMG;

    hipMemsetAsync(d_ws, 0, G * V * sizeof(unsigned int), stream);
    vq_prep<<<80, 256, 0, stream>>>(Wm, img);
    vq_main<<<2048, 512, 0, stream>>>(hs, img, bv, cbv, out, hist);
    vq_ppl<<<1, 64, 0, stream>>>(hist, out + (size_t)BT * G * Dg);
}